// Round 1
// baseline (80.276 us; speedup 1.0000x reference)
//
#include <hip/hip_runtime.h>
#include <math.h>

#define C_CH 256
#define KTOP 26
#define HWSZ 3136            // 56*56
#define NPIX 100352          // 32*3136
#define CHW  (C_CH * HWSZ)

__global__ __launch_bounds__(256) void kwinners_kernel(
    const float* __restrict__ x, const float* __restrict__ duty,
    const float* __restrict__ bsp, float* __restrict__ out)
{
    __shared__ float s[C_CH];
    const int t = threadIdx.x;
    {
        // scale = exp(-bs * duty[c]); fp32 multiply (matches jnp), exp in
        // double then round to fp32 -> correctly-rounded fp32 exp.
        float bs = bsp[0];
        float m = -(bs * duty[t]);
        s[t] = (float)exp((double)m);
    }
    __syncthreads();

    const int p  = blockIdx.x * 256 + t;
    const int b  = p / HWSZ;
    const int hw = p - b * HWSZ;
    const float* xp = x   + (size_t)b * CHW + hw;
    float*       op = out + (size_t)b * CHW + hw;

    // two top-26 descending-sorted lists (even / odd channels) for ILP=2
    float a0[KTOP], a1[KTOP];
#pragma unroll
    for (int j = 0; j < KTOP; ++j) { a0[j] = -INFINITY; a1[j] = -INFINITY; }

#pragma unroll 8
    for (int c = 0; c < C_CH; c += 2) {
        float v0 = xp[(size_t)c       * HWSZ] * s[c];
        float v1 = xp[(size_t)(c + 1) * HWSZ] * s[c + 1];
#pragma unroll
        for (int j = 0; j < KTOP; ++j) {
            float l0 = fminf(a0[j], v0); a0[j] = fmaxf(a0[j], v0); v0 = l0;
            float l1 = fminf(a1[j], v1); a1[j] = fmaxf(a1[j], v1); v1 = l1;
        }
    }

    // Merge: build bitonic-64 = [a0 desc, pad -inf][a1 asc (reversed), pad]
    // and extract rank 25 (26th largest) via half-cleaner cascade.
    float h[32];
#pragma unroll
    for (int i = 0; i < 32; ++i) {
        float u = (i < KTOP)        ? a0[i]      : -INFINITY;   // seq[i]
        float w = (31 - i < KTOP)   ? a1[31 - i] : -INFINITY;   // seq[32+i]
        h[i] = fmaxf(u, w);          // k=32: keep max-half (ranks 0..31), r=25
    }
    float l16[16];
#pragma unroll
    for (int i = 0; i < 16; ++i) l16[i] = fminf(h[i], h[i + 16]);  // r=25 -> min-half, r=9
    float l8[8];
#pragma unroll
    for (int i = 0; i < 8; ++i)  l8[i]  = fminf(l16[i], l16[i + 8]); // r=9 -> min-half, r=1
    float h4[4];
#pragma unroll
    for (int i = 0; i < 4; ++i)  h4[i]  = fmaxf(l8[i], l8[i + 4]);   // r=1 -> max-half, r=1
    float h2[2];
#pragma unroll
    for (int i = 0; i < 2; ++i)  h2[i]  = fmaxf(h4[i], h4[i + 2]);   // r=1 -> max-half, r=1
    const float thr = fminf(h2[0], h2[1]);                           // rank 1 of 2 = min

    // Pass 2: apply mask (re-read served by L3), write output.
#pragma unroll 8
    for (int c = 0; c < C_CH; ++c) {
        float v  = xp[(size_t)c * HWSZ];
        float bv = v * s[c];
        op[(size_t)c * HWSZ] = (bv >= thr) ? v : 0.0f;
    }
}

extern "C" void kernel_launch(void* const* d_in, const int* in_sizes, int n_in,
                              void* d_out, int out_size, void* d_ws, size_t ws_size,
                              hipStream_t stream) {
    const float* x    = (const float*)d_in[0];
    const float* duty = (const float*)d_in[1];
    // d_in[2] = k (int, ==26 hardcoded), d_in[3] = boost_strength (float)
    const float* bs   = (const float*)d_in[3];
    float* out = (float*)d_out;

    hipLaunchKernelGGL(kwinners_kernel, dim3(NPIX / 256), dim3(256), 0, stream,
                       x, duty, bs, out);
}

// Round 2
// 63.908 us; speedup vs baseline: 1.2561x; 1.2561x over previous
//
#include <hip/hip_runtime.h>
#include <math.h>

#define C_CH 256
#define KTOP 26
#define HWSZ 3136            // 56*56
#define NPIX 100352          // 32*3136
#define CHW  (C_CH * HWSZ)
#define PIX_PER_BLK 64
#define CPQ 64               // channels per thread (C_CH / 4)

// Sort a bitonic-32 sequence into descending order in place.
// Half-cleaner cascade, distances 16,8,4,2,1. Fully static indexing.
__device__ __forceinline__ void sort_bitonic32_desc(float h[32]) {
#pragma unroll
    for (int i = 0; i < 16; ++i) {
        float mx = fmaxf(h[i], h[i + 16]), mn = fminf(h[i], h[i + 16]);
        h[i] = mx; h[i + 16] = mn;
    }
#pragma unroll
    for (int g = 0; g < 32; g += 16)
#pragma unroll
        for (int i = 0; i < 8; ++i) {
            int u = g + i, v = g + i + 8;
            float mx = fmaxf(h[u], h[v]), mn = fminf(h[u], h[v]);
            h[u] = mx; h[v] = mn;
        }
#pragma unroll
    for (int g = 0; g < 32; g += 8)
#pragma unroll
        for (int i = 0; i < 4; ++i) {
            int u = g + i, v = g + i + 4;
            float mx = fmaxf(h[u], h[v]), mn = fminf(h[u], h[v]);
            h[u] = mx; h[v] = mn;
        }
#pragma unroll
    for (int g = 0; g < 32; g += 4)
#pragma unroll
        for (int i = 0; i < 2; ++i) {
            int u = g + i, v = g + i + 2;
            float mx = fmaxf(h[u], h[v]), mn = fminf(h[u], h[v]);
            h[u] = mx; h[v] = mn;
        }
#pragma unroll
    for (int g = 0; g < 32; g += 2) {
        float mx = fmaxf(h[g], h[g + 1]), mn = fminf(h[g], h[g + 1]);
        h[g] = mx; h[g + 1] = mn;
    }
}

__global__ __launch_bounds__(256) void kwinners_kernel(
    const float* __restrict__ x, const float* __restrict__ duty,
    const float* __restrict__ bsp, float* __restrict__ out)
{
    __shared__ float s[C_CH];
    __shared__ float lbuf[2][PIX_PER_BLK][27];   // pad 27: gcd(27,32)=1 -> 2-way (free)
    __shared__ float thr_lds[PIX_PER_BLK];

    const int t = threadIdx.x;
    {
        // scale = exp(-bs * duty[c]); fp32 mul (matches jnp), exp in double
        // rounded to fp32 -> correctly-rounded fp32 exp. (absmax=0 verified R1)
        float bs = bsp[0];
        float m = -(bs * duty[t]);
        s[t] = (float)exp((double)m);
    }
    __syncthreads();

    const int q   = t >> 6;                 // wave id within block = channel quarter
    const int pl  = t & 63;                 // pixel lane
    const int blk = blockIdx.x;
    const int b   = blk / 49;               // 3136/64 = 49 blocks per batch image
    const int hw  = (blk - b * 49) * 64 + pl;
    const int c0  = q * CPQ;

    const float* xp = x   + (size_t)b * CHW + (size_t)c0 * HWSZ + hw;
    float*       op = out + (size_t)b * CHW + (size_t)c0 * HWSZ + hw;
    const float* sc = s + c0;

    // Per-thread sorted (desc) top-26 of this thread's 64 channels.
    float a[KTOP];
#pragma unroll
    for (int j = 0; j < KTOP; ++j) a[j] = -INFINITY;

#pragma unroll 8
    for (int i = 0; i < CPQ; ++i) {
        float v = xp[(size_t)i * HWSZ] * sc[i];
#pragma unroll
        for (int j = 0; j < KTOP; ++j) {
            float l = fminf(a[j], v); a[j] = fmaxf(a[j], v); v = l;
        }
    }

    // Round 1 publish: q1 -> lbuf[0], q3 -> lbuf[1]
    if (q & 1) {
        float* dst = lbuf[q >> 1][pl];
#pragma unroll
        for (int j = 0; j < KTOP; ++j) dst[j] = a[j];
    }
    __syncthreads();

    // Round 1 merge (q0: own+q1, q2: own+q3) -> sorted top-26 of 128 channels.
    float m26[KTOP];
    if (!(q & 1)) {
        const float* src = lbuf[q >> 1][pl];
        float h[32];
        // [a desc pad32][reverse(src) asc pad32] is bitonic-64; max-half keeps
        // ranks 0..31 and is itself bitonic.
#pragma unroll
        for (int i = 0; i < 32; ++i) {
            float u = (i < KTOP)      ? a[i]           : -INFINITY;
            float w = (31 - i < KTOP) ? src[31 - i]    : -INFINITY;
            h[i] = fmaxf(u, w);
        }
        sort_bitonic32_desc(h);
#pragma unroll
        for (int j = 0; j < KTOP; ++j) m26[j] = h[j];
        if (q == 2) {
            float* dst = lbuf[1][pl];
#pragma unroll
            for (int j = 0; j < KTOP; ++j) dst[j] = m26[j];
        }
    }
    __syncthreads();

    // Round 2 (q0 only): rank-25 (26th largest) of merge(m26, q2's list).
    // Verified cascade from round 0: max32 -> min16 -> min8 -> max4 -> max2 -> min.
    if (q == 0) {
        const float* src = lbuf[1][pl];
        float h[32];
#pragma unroll
        for (int i = 0; i < 32; ++i) {
            float u = (i < KTOP)      ? m26[i]      : -INFINITY;
            float w = (31 - i < KTOP) ? src[31 - i] : -INFINITY;
            h[i] = fmaxf(u, w);                       // ranks 0..31, target r=25
        }
        float l16[16];
#pragma unroll
        for (int i = 0; i < 16; ++i) l16[i] = fminf(h[i], h[i + 16]);   // r=9
        float l8[8];
#pragma unroll
        for (int i = 0; i < 8; ++i)  l8[i]  = fminf(l16[i], l16[i + 8]); // r=1
        float h4[4];
#pragma unroll
        for (int i = 0; i < 4; ++i)  h4[i]  = fmaxf(l8[i], l8[i + 4]);   // r=1
        float h2[2];
#pragma unroll
        for (int i = 0; i < 2; ++i)  h2[i]  = fmaxf(h4[i], h4[i + 2]);   // r=1
        thr_lds[pl] = fminf(h2[0], h2[1]);
    }
    __syncthreads();

    const float thr = thr_lds[pl];

    // Pass 2: re-read own 64 channels (L3-resident), apply mask, write.
#pragma unroll 8
    for (int i = 0; i < CPQ; ++i) {
        float v  = xp[(size_t)i * HWSZ];
        float bv = v * sc[i];
        op[(size_t)i * HWSZ] = (bv >= thr) ? v : 0.0f;
    }
}

extern "C" void kernel_launch(void* const* d_in, const int* in_sizes, int n_in,
                              void* d_out, int out_size, void* d_ws, size_t ws_size,
                              hipStream_t stream) {
    const float* x    = (const float*)d_in[0];
    const float* duty = (const float*)d_in[1];
    // d_in[2] = k (int, ==26 hardcoded), d_in[3] = boost_strength (float)
    const float* bs   = (const float*)d_in[3];
    float* out = (float*)d_out;

    hipLaunchKernelGGL(kwinners_kernel, dim3(NPIX / PIX_PER_BLK), dim3(256), 0,
                       stream, x, duty, bs, out);
}

// Round 3
// 50.138 us; speedup vs baseline: 1.6011x; 1.2746x over previous
//
#include <hip/hip_runtime.h>
#include <math.h>

#define C_CH 256
#define KTOP 26
#define HWSZ 3136            // 56*56
#define NPIX 100352          // 32*3136
#define CHW  (C_CH * HWSZ)
#define PIX_PER_BLK 64
#define CPQ 64               // channels per thread (C_CH / 4)

__device__ __forceinline__ void ce_desc(float& a, float& b) {
    float mx = fmaxf(a, b); float mn = fminf(a, b); a = mx; b = mn;
}
__device__ __forceinline__ void ce_asc(float& a, float& b) {
    float mn = fminf(a, b); float mx = fmaxf(a, b); a = mn; b = mx;
}

// Full bitonic sort of 32 values -> descending. 240 compare-exchanges,
// all indices compile-time after unroll.
__device__ __forceinline__ void sort32_desc(float* v) {
#pragma unroll
    for (int k = 2; k <= 32; k <<= 1) {
#pragma unroll
        for (int j = k >> 1; j > 0; j >>= 1) {
#pragma unroll
            for (int i = 0; i < 32; ++i) {
                int l = i ^ j;
                if (l > i) {
                    if ((i & k) == 0) ce_desc(v[i], v[l]);
                    else              ce_asc(v[i], v[l]);
                }
            }
        }
    }
}

// Clean an already-bitonic 32 sequence -> descending. 80 CE (j=16..1).
__device__ __forceinline__ void clean32_desc(float* v) {
#pragma unroll
    for (int j = 16; j > 0; j >>= 1) {
#pragma unroll
        for (int i = 0; i < 32; ++i) {
            int l = i ^ j;
            if (l > i) ce_desc(v[i], v[l]);
        }
    }
}

__global__ __launch_bounds__(256) void kwinners_kernel(
    const float* __restrict__ x, const float* __restrict__ duty,
    const float* __restrict__ bsp, float* __restrict__ out)
{
    __shared__ float s[C_CH];
    __shared__ float lbuf[2][PIX_PER_BLK][27];   // pad 27: gcd(27,32)=1
    __shared__ float thr_lds[PIX_PER_BLK];

    const int t = threadIdx.x;
    {
        // scale = exp(-bs * duty[c]); fp32 mul (matches jnp), exp in double
        // rounded to fp32 -> correctly-rounded fp32 exp. (absmax=0, R1/R2)
        float bs = bsp[0];
        float m = -(bs * duty[t]);
        s[t] = (float)exp((double)m);
    }
    __syncthreads();

    const int q   = t >> 6;                 // wave id = channel quarter
    const int pl  = t & 63;                 // pixel lane
    const int blk = blockIdx.x;
    const int b   = blk / 49;               // 3136/64 = 49 blocks per image
    const int hw  = (blk - b * 49) * 64 + pl;
    const int c0  = q * CPQ;

    const float* xp = x   + (size_t)b * CHW + (size_t)c0 * HWSZ + hw;
    float*       op = out + (size_t)b * CHW + (size_t)c0 * HWSZ + hw;
    const float* sc = s + c0;

    // ---- Pass 1: sorted top-32 (desc) of this thread's 64 channels ----
    float v[CPQ];
#pragma unroll
    for (int i = 0; i < CPQ; ++i) v[i] = xp[(size_t)i * HWSZ] * sc[i];

    sort32_desc(v);         // v[0:32] desc
    sort32_desc(v + 32);    // v[32:64] desc

    // merge two desc-32: [v0 desc | reversed v1 asc] is bitonic-64;
    // max-half keeps ranks 0..31 (bitonic), then clean -> sorted desc.
    float a[32];
#pragma unroll
    for (int i = 0; i < 32; ++i) a[i] = fmaxf(v[i], v[63 - i]);
    clean32_desc(a);

    // ---- Round 1 publish: q1 -> lbuf[0], q3 -> lbuf[1] (top-26 only) ----
    if (q & 1) {
        float* dst = lbuf[q >> 1][pl];
#pragma unroll
        for (int j = 0; j < KTOP; ++j) dst[j] = a[j];
    }
    __syncthreads();

    // ---- Round 1 merge (q0: own+q1, q2: own+q3) -> sorted top-26 of 128 ----
    float m26[KTOP];
    if (!(q & 1)) {
        const float* src = lbuf[q >> 1][pl];
        float h[32];
#pragma unroll
        for (int i = 0; i < 32; ++i) {
            float u = (i < KTOP)      ? a[i]        : -INFINITY;
            float w = (31 - i < KTOP) ? src[31 - i] : -INFINITY;
            h[i] = fmaxf(u, w);
        }
        clean32_desc(h);
#pragma unroll
        for (int j = 0; j < KTOP; ++j) m26[j] = h[j];
        if (q == 2) {
            float* dst = lbuf[1][pl];
#pragma unroll
            for (int j = 0; j < KTOP; ++j) dst[j] = m26[j];
        }
    }
    __syncthreads();

    // ---- Round 2 (q0): rank-25 of merge(m26, q2 list) via cascade ----
    if (q == 0) {
        const float* src = lbuf[1][pl];
        float h[32];
#pragma unroll
        for (int i = 0; i < 32; ++i) {
            float u = (i < KTOP)      ? m26[i]      : -INFINITY;
            float w = (31 - i < KTOP) ? src[31 - i] : -INFINITY;
            h[i] = fmaxf(u, w);                       // ranks 0..31, r=25
        }
        float l16[16];
#pragma unroll
        for (int i = 0; i < 16; ++i) l16[i] = fminf(h[i], h[i + 16]);   // r=9
        float l8[8];
#pragma unroll
        for (int i = 0; i < 8; ++i)  l8[i]  = fminf(l16[i], l16[i + 8]); // r=1
        float h4[4];
#pragma unroll
        for (int i = 0; i < 4; ++i)  h4[i]  = fmaxf(l8[i], l8[i + 4]);   // r=1
        float h2[2];
#pragma unroll
        for (int i = 0; i < 2; ++i)  h2[i]  = fmaxf(h4[i], h4[i + 2]);   // r=1
        thr_lds[pl] = fminf(h2[0], h2[1]);
    }
    __syncthreads();

    const float thr = thr_lds[pl];

    // ---- Pass 2: re-read own 64 channels (cache-resident), mask, write ----
#pragma unroll 8
    for (int i = 0; i < CPQ; ++i) {
        float xv = xp[(size_t)i * HWSZ];
        float bv = xv * sc[i];
        op[(size_t)i * HWSZ] = (bv >= thr) ? xv : 0.0f;
    }
}

extern "C" void kernel_launch(void* const* d_in, const int* in_sizes, int n_in,
                              void* d_out, int out_size, void* d_ws, size_t ws_size,
                              hipStream_t stream) {
    const float* x    = (const float*)d_in[0];
    const float* duty = (const float*)d_in[1];
    // d_in[2] = k (int, ==26 hardcoded), d_in[3] = boost_strength (float)
    const float* bs   = (const float*)d_in[3];
    float* out = (float*)d_out;

    hipLaunchKernelGGL(kwinners_kernel, dim3(NPIX / PIX_PER_BLK), dim3(256), 0,
                       stream, x, duty, bs, out);
}

// Round 4
// 44.148 us; speedup vs baseline: 1.8183x; 1.1357x over previous
//
#include <hip/hip_runtime.h>
#include <math.h>

#define C_CH 256
#define KTOP 26
#define HWSZ 3136            // 56*56
#define NPIX 100352          // 32*3136
#define CHW  (C_CH * HWSZ)
#define PIX_PER_BLK 64
#define CPT 32               // channels per thread (C_CH / 8)

__device__ __forceinline__ void ce_desc(float& a, float& b) {
    float mx = fmaxf(a, b); float mn = fminf(a, b); a = mx; b = mn;
}
__device__ __forceinline__ void ce_asc(float& a, float& b) {
    float mn = fminf(a, b); float mx = fmaxf(a, b); a = mn; b = mx;
}

// Full bitonic sort of 32 values -> descending. 240 CE, static indices.
__device__ __forceinline__ void sort32_desc(float* v) {
#pragma unroll
    for (int k = 2; k <= 32; k <<= 1) {
#pragma unroll
        for (int j = k >> 1; j > 0; j >>= 1) {
#pragma unroll
            for (int i = 0; i < 32; ++i) {
                int l = i ^ j;
                if (l > i) {
                    if ((i & k) == 0) ce_desc(v[i], v[l]);
                    else              ce_asc(v[i], v[l]);
                }
            }
        }
    }
}

// Clean an already-bitonic 32 sequence -> descending. 80 CE.
__device__ __forceinline__ void clean32_desc(float* v) {
#pragma unroll
    for (int j = 16; j > 0; j >>= 1) {
#pragma unroll
        for (int i = 0; i < 32; ++i) {
            int l = i ^ j;
            if (l > i) ce_desc(v[i], v[l]);
        }
    }
}

// Merge own desc-26 list (in a[0..25]) with LDS desc-26 list -> a = top-26
// sorted of the union. [a desc pad32 | rev(src) asc pad32] is bitonic-64;
// max-half keeps ranks 0..31 (bitonic), clean -> sorted desc.
__device__ __forceinline__ void merge26(float* a, const float* __restrict__ src) {
    float h[32];
#pragma unroll
    for (int i = 0; i < 32; ++i) {
        float u = (i < KTOP)      ? a[i]        : -INFINITY;
        float w = (31 - i < KTOP) ? src[31 - i] : -INFINITY;
        h[i] = fmaxf(u, w);
    }
    clean32_desc(h);
#pragma unroll
    for (int j = 0; j < KTOP; ++j) a[j] = h[j];
}

__global__ __launch_bounds__(512, 4) void kwinners_kernel(
    const float* __restrict__ x, const float* __restrict__ duty,
    const float* __restrict__ bsp, float* __restrict__ out)
{
    __shared__ float s[C_CH];
    __shared__ float lbuf[4][PIX_PER_BLK][27];   // stride 27: 2-way max (free)
    __shared__ float thr_lds[PIX_PER_BLK];

    const int t = threadIdx.x;
    if (t < C_CH) {
        // scale = exp(-bs * duty[c]); fp32 mul (matches jnp), exp in double
        // rounded to fp32 -> correctly-rounded fp32 exp. (absmax=0, R1-R3)
        float bs = bsp[0];
        float m = -(bs * duty[t]);
        s[t] = (float)exp((double)m);
    }
    __syncthreads();

    const int w   = t >> 6;                 // wave id = channel eighth (0..7)
    const int pl  = t & 63;                 // pixel lane
    const int blk = blockIdx.x;
    const int b   = blk / 49;               // 3136/64 = 49 blocks per image
    const int hw  = (blk - b * 49) * 64 + pl;
    const int c0  = w * CPT;

    const float* xp = x   + (size_t)b * CHW + (size_t)c0 * HWSZ + hw;
    float*       op = out + (size_t)b * CHW + (size_t)c0 * HWSZ + hw;
    const float* sc = s + c0;

    // ---- Load originals (kept in regs for the final write), boost, sort ----
    float o[CPT];
#pragma unroll
    for (int i = 0; i < CPT; ++i) o[i] = xp[(size_t)i * HWSZ];

    float v[CPT];
#pragma unroll
    for (int i = 0; i < CPT; ++i) v[i] = o[i] * sc[i];

    sort32_desc(v);                         // own 32 channels, desc

    // ---- Level 1: waves (0,1)(2,3)(4,5)(6,7); odd publishes top-26 ----
    if (w & 1) {
        float* dst = lbuf[w >> 1][pl];
#pragma unroll
        for (int j = 0; j < KTOP; ++j) dst[j] = v[j];
    }
    __syncthreads();

    if (!(w & 1)) {
        merge26(v, lbuf[w >> 1][pl]);       // v[0..25] = top-26 of 64 ch
        if (w == 2 || w == 6) {             // publish for level 2
            float* dst = lbuf[w >> 1][pl];  // w2->buf1, w6->buf3 (own source)
#pragma unroll
            for (int j = 0; j < KTOP; ++j) dst[j] = v[j];
        }
    }
    __syncthreads();

    // ---- Level 2: waves 0,4 merge -> top-26 of 128 ch ----
    if (w == 0 || w == 4) {
        merge26(v, lbuf[(w >> 1) + 1][pl]); // w0<-buf1, w4<-buf3
        if (w == 4) {
            float* dst = lbuf[2][pl];       // wave4-private since level 1
#pragma unroll
            for (int j = 0; j < KTOP; ++j) dst[j] = v[j];
        }
    }
    __syncthreads();

    // ---- Level 3 (wave 0): rank-25 of merge(v, buf2) via cascade ----
    if (w == 0) {
        const float* src = lbuf[2][pl];
        float h[32];
#pragma unroll
        for (int i = 0; i < 32; ++i) {
            float u = (i < KTOP)      ? v[i]        : -INFINITY;
            float wv = (31 - i < KTOP) ? src[31 - i] : -INFINITY;
            h[i] = fmaxf(u, wv);                      // ranks 0..31, r=25
        }
        float l16[16];
#pragma unroll
        for (int i = 0; i < 16; ++i) l16[i] = fminf(h[i], h[i + 16]);    // r=9
        float l8[8];
#pragma unroll
        for (int i = 0; i < 8; ++i)  l8[i]  = fminf(l16[i], l16[i + 8]); // r=1
        float h4[4];
#pragma unroll
        for (int i = 0; i < 4; ++i)  h4[i]  = fmaxf(l8[i], l8[i + 4]);   // r=1
        float h2[2];
#pragma unroll
        for (int i = 0; i < 2; ++i)  h2[i]  = fmaxf(h4[i], h4[i + 2]);   // r=1
        thr_lds[pl] = fminf(h2[0], h2[1]);
    }
    __syncthreads();

    const float thr = thr_lds[pl];

    // ---- Write from registers (no global re-read) ----
#pragma unroll
    for (int i = 0; i < CPT; ++i) {
        float bv = o[i] * sc[i];
        op[(size_t)i * HWSZ] = (bv >= thr) ? o[i] : 0.0f;
    }
}

extern "C" void kernel_launch(void* const* d_in, const int* in_sizes, int n_in,
                              void* d_out, int out_size, void* d_ws, size_t ws_size,
                              hipStream_t stream) {
    const float* x    = (const float*)d_in[0];
    const float* duty = (const float*)d_in[1];
    // d_in[2] = k (int, ==26 hardcoded), d_in[3] = boost_strength (float)
    const float* bs   = (const float*)d_in[3];
    float* out = (float*)d_out;

    hipLaunchKernelGGL(kwinners_kernel, dim3(NPIX / PIX_PER_BLK), dim3(512), 0,
                       stream, x, duty, bs, out);
}